// Round 1
// baseline (946.408 us; speedup 1.0000x reference)
//
#include <hip/hip_runtime.h>

#define NN 100000
#define NE 1600000
#define DD 64
#define HH 128
#define NLAYERS 4
#define NGRAPH 64

// ---------------- CSR build ----------------

__global__ void k_count(const int* __restrict__ dst, int* __restrict__ cnt) {
  int e = blockIdx.x * 256 + threadIdx.x;
  atomicAdd(&cnt[dst[e]], 1);
}

__global__ void k_scan1(const int* __restrict__ cnt, int* __restrict__ offs,
                        int* __restrict__ bsum, int n) {
  __shared__ int s[256];
  int t = threadIdx.x;
  int i = blockIdx.x * 256 + t;
  int v = (i < n) ? cnt[i] : 0;
  s[t] = v;
  __syncthreads();
  for (int off = 1; off < 256; off <<= 1) {
    int x = (t >= off) ? s[t - off] : 0;
    __syncthreads();
    s[t] += x;
    __syncthreads();
  }
  if (i < n) offs[i] = s[t] - v;          // exclusive within block
  if (t == 255) bsum[blockIdx.x] = s[255]; // block total
}

__global__ void k_scan2(int* bsum, int nb) {
  __shared__ int s[512];
  int t = threadIdx.x;
  int v = (t < nb) ? bsum[t] : 0;
  s[t] = v;
  __syncthreads();
  for (int off = 1; off < 512; off <<= 1) {
    int x = (t >= off) ? s[t - off] : 0;
    __syncthreads();
    s[t] += x;
    __syncthreads();
  }
  if (t < nb) bsum[t] = s[t] - v;          // exclusive over blocks
}

__global__ void k_scan3(int* __restrict__ offs, const int* __restrict__ bsum,
                        int* __restrict__ cursor, int n) {
  int i = blockIdx.x * 256 + threadIdx.x;
  if (i < n) {
    int o = offs[i] + bsum[i >> 8];
    offs[i] = o;
    cursor[i] = o;
  }
}

__global__ void k_fill(const int* __restrict__ src, const int* __restrict__ dst,
                       int* __restrict__ cursor, int* __restrict__ csr) {
  int e = blockIdx.x * 256 + threadIdx.x;
  int pos = atomicAdd(&cursor[dst[e]], 1);
  csr[pos] = src[e];
}

// ---------------- lin_in: h = x @ W_in + b_in ----------------
// one wave computes 4 nodes x 64 cols; lane = col
__global__ void k_lin_in(const float* __restrict__ x, const float* __restrict__ W,
                         const float* __restrict__ b, float* __restrict__ h) {
  int t = threadIdx.x;
  int c = t & 63;
  int wv = blockIdx.x * 4 + (t >> 6);
  int n0 = wv * 4;
  float bc = b[c];
  float a0 = bc, a1 = bc, a2 = bc, a3 = bc;
  const float* x0 = x + n0 * 64;
#pragma unroll 8
  for (int k = 0; k < 64; k++) {
    float w = W[k * 64 + c];
    a0 += x0[k] * w;
    a1 += x0[64 + k] * w;
    a2 += x0[128 + k] * w;
    a3 += x0[192 + k] * w;
  }
  h[(n0 + 0) * 64 + c] = a0;
  h[(n0 + 1) * 64 + c] = a1;
  h[(n0 + 2) * 64 + c] = a2;
  h[(n0 + 3) * 64 + c] = a3;
}

// ---------------- aggregate: agg[i] = sum_{e: dst=i} relu(h[src]) ----------------
// 16 threads per node, each owns 4 contiguous floats
__global__ void k_agg(const float* __restrict__ h, const int* __restrict__ csr,
                      const int* __restrict__ offs, const int* __restrict__ cnt,
                      float* __restrict__ agg) {
  int t = blockIdx.x * 256 + threadIdx.x;
  int node = t >> 4;
  int q = (t & 15) * 4;
  int start = offs[node];
  int deg = cnt[node];
  float4 acc = {0.f, 0.f, 0.f, 0.f};
  for (int j = 0; j < deg; j++) {
    int s = csr[start + j];
    float4 v = *reinterpret_cast<const float4*>(&h[s * 64 + q]);
    acc.x += fmaxf(v.x, 0.f);
    acc.y += fmaxf(v.y, 0.f);
    acc.z += fmaxf(v.z, 0.f);
    acc.w += fmaxf(v.w, 0.f);
  }
  *reinterpret_cast<float4*>(&agg[node * 64 + q]) = acc;
}

// ---------------- fused MLP per layer ----------------
// z = (1+eps)*h + agg ; t = relu(LN(z@W1+b1)) ; h += t@W2 + b2
// 32 nodes / block, 256 threads
__global__ __launch_bounds__(256) void k_mlp(
    float* __restrict__ h, const float* __restrict__ agg,
    const float* __restrict__ W1l, const float* __restrict__ b1l,
    const float* __restrict__ gl, const float* __restrict__ btl,
    const float* __restrict__ W2l, const float* __restrict__ b2l,
    const float* __restrict__ epsl) {
  __shared__ __align__(16) float sW[8192];       // W1 then W2 (time-shared)
  __shared__ __align__(16) float sZ[32 * 64];
  __shared__ __align__(16) float sR[32 * 128];
  __shared__ float sb1[128], sg[128], sbt[128], sb2[64];

  int t = threadIdx.x;
  int nbase = blockIdx.x * 32;

  // stage W1 + params
  for (int i = t; i < 2048; i += 256)
    ((float4*)sW)[i] = ((const float4*)W1l)[i];
  if (t < 128) { sb1[t] = b1l[t]; sg[t] = gl[t]; sbt[t] = btl[t]; }
  if (t < 64) sb2[t] = b2l[t];
  float epsv = 1.0f + *epsl;

  // z = (1+eps)*h + agg  (2048 floats, 8 per thread)
  {
    int base = t * 8;
    int node = base >> 6;
    int d = base & 63;
    const float4* hp = (const float4*)&h[(nbase + node) * 64 + d];
    const float4* ap = (const float4*)&agg[(nbase + node) * 64 + d];
    float4 h0 = hp[0], h1 = hp[1], a0 = ap[0], a1 = ap[1];
    float4 z0, z1;
    z0.x = epsv * h0.x + a0.x; z0.y = epsv * h0.y + a0.y;
    z0.z = epsv * h0.z + a0.z; z0.w = epsv * h0.w + a0.w;
    z1.x = epsv * h1.x + a1.x; z1.y = epsv * h1.y + a1.y;
    z1.z = epsv * h1.z + a1.z; z1.w = epsv * h1.w + a1.w;
    ((float4*)sZ)[t * 2] = z0;
    ((float4*)sZ)[t * 2 + 1] = z1;
  }
  __syncthreads();

  // phase B: z1 = z @ W1 + b1 for 4 nodes x 4 cols per thread
  int cg = t & 31;         // col group: cols cg*4..cg*4+3
  int ng = t >> 5;         // node group: nodes ng*4..ng*4+3
  float acc[4][4];
#pragma unroll
  for (int i = 0; i < 4; i++)
#pragma unroll
    for (int j = 0; j < 4; j++) acc[i][j] = sb1[cg * 4 + j];

#pragma unroll 4
  for (int k = 0; k < 64; k++) {
    float4 w = ((float4*)sW)[k * 32 + cg];
#pragma unroll
    for (int i = 0; i < 4; i++) {
      float z = sZ[(ng * 4 + i) * 64 + k];
      acc[i][0] += z * w.x;
      acc[i][1] += z * w.y;
      acc[i][2] += z * w.z;
      acc[i][3] += z * w.w;
    }
  }

  // LayerNorm over 128 cols (spread across 32 lanes within half-wave) + relu
  float ps[4], pq[4];
#pragma unroll
  for (int i = 0; i < 4; i++) {
    ps[i] = acc[i][0] + acc[i][1] + acc[i][2] + acc[i][3];
    pq[i] = acc[i][0] * acc[i][0] + acc[i][1] * acc[i][1] +
            acc[i][2] * acc[i][2] + acc[i][3] * acc[i][3];
  }
#pragma unroll
  for (int m = 1; m <= 16; m <<= 1) {
#pragma unroll
    for (int i = 0; i < 4; i++) {
      ps[i] += __shfl_xor(ps[i], m);
      pq[i] += __shfl_xor(pq[i], m);
    }
  }
#pragma unroll
  for (int i = 0; i < 4; i++) {
    float mu = ps[i] * (1.0f / 128.0f);
    float var = pq[i] * (1.0f / 128.0f) - mu * mu;
    float rs = rsqrtf(var + 1e-5f);
    float4 r;
    float* rp = &r.x;
#pragma unroll
    for (int j = 0; j < 4; j++) {
      int c = cg * 4 + j;
      float v = (acc[i][j] - mu) * rs * sg[c] + sbt[c];
      rp[j] = fmaxf(v, 0.f);
    }
    ((float4*)sR)[((ng * 4 + i) * 128 + cg * 4) / 4] = r;
  }
  __syncthreads();

  // stage W2 (overwrites sW)
  for (int i = t; i < 2048; i += 256)
    ((float4*)sW)[i] = ((const float4*)W2l)[i];
  __syncthreads();

  // phase C: out = r @ W2 + b2 + h ; 2 nodes x 4 cols per thread
  int cg2 = t & 15;
  int ng2 = t >> 4;
  int n0 = ng2 * 2, n1 = n0 + 1;
  float a0[4], a1[4];
#pragma unroll
  for (int j = 0; j < 4; j++) { a0[j] = sb2[cg2 * 4 + j]; a1[j] = a0[j]; }
#pragma unroll 4
  for (int k = 0; k < 128; k++) {
    float4 w = ((float4*)sW)[k * 16 + cg2];
    float r0 = sR[n0 * 128 + k];
    float r1 = sR[n1 * 128 + k];
    a0[0] += r0 * w.x; a0[1] += r0 * w.y; a0[2] += r0 * w.z; a0[3] += r0 * w.w;
    a1[0] += r1 * w.x; a1[1] += r1 * w.y; a1[2] += r1 * w.z; a1[3] += r1 * w.w;
  }
  {
    float4 h0 = *(const float4*)&h[(nbase + n0) * 64 + cg2 * 4];
    float4 h1 = *(const float4*)&h[(nbase + n1) * 64 + cg2 * 4];
    float4 o0, o1;
    o0.x = h0.x + a0[0]; o0.y = h0.y + a0[1]; o0.z = h0.z + a0[2]; o0.w = h0.w + a0[3];
    o1.x = h1.x + a1[0]; o1.y = h1.y + a1[1]; o1.z = h1.z + a1[2]; o1.w = h1.w + a1[3];
    *(float4*)&h[(nbase + n0) * 64 + cg2 * 4] = o0;
    *(float4*)&h[(nbase + n1) * 64 + cg2 * 4] = o1;
  }
}

// ---------------- pooling: pooled[g] = sum_{batch[n]==g} h[n] ----------------
// batch sorted: per-wave run-length accumulate, one wave = 64 nodes x 64 dims
__global__ void k_pool(const float* __restrict__ h, const int* __restrict__ batch,
                       float* __restrict__ pooled, int n) {
  int t = threadIdx.x;
  int d = t & 63;
  int w = t >> 6;
  int n0 = blockIdx.x * 256 + w * 64;
  float acc = 0.f;
  int prev = -1;
  for (int i = 0; i < 64; i++) {
    int nn = n0 + i;
    if (nn >= n) break;
    int g = batch[nn];
    if (g != prev) {
      if (prev >= 0) atomicAdd(&pooled[prev * 64 + d], acc);
      prev = g;
      acc = 0.f;
    }
    acc += h[nn * 64 + d];
  }
  if (prev >= 0) atomicAdd(&pooled[prev * 64 + d], acc);
}

// ---------------- output MLP ----------------
__global__ void k_out(const float* __restrict__ pooled, const float* __restrict__ Wo1,
                      const float* __restrict__ bo1, const float* __restrict__ Wo2,
                      const float* __restrict__ bo2, float* __restrict__ out) {
  __shared__ __align__(16) float sP[64 * 64];
  int t = threadIdx.x;
  for (int i = t; i < 1024; i += 256)
    ((float4*)sP)[i] = ((const float4*)pooled)[i];
  __syncthreads();
  int g = t >> 2;
  int q = t & 3;
  float acc = 0.f;
  for (int c = q * 32; c < q * 32 + 32; c++) {
    float t1 = bo1[c];
#pragma unroll 8
    for (int k = 0; k < 64; k++) t1 += sP[g * 64 + k] * Wo1[k * 128 + c];
    acc += fmaxf(t1, 0.f) * Wo2[c];
  }
  acc += __shfl_xor(acc, 1);
  acc += __shfl_xor(acc, 2);
  if (q == 0) out[g] = acc + bo2[0];
}

// ---------------- launch ----------------

static inline char* align_up(char* p, size_t a) {
  return (char*)(((uintptr_t)p + a - 1) & ~(uintptr_t)(a - 1));
}

extern "C" void kernel_launch(void* const* d_in, const int* in_sizes, int n_in,
                              void* d_out, int out_size, void* d_ws, size_t ws_size,
                              hipStream_t stream) {
  const float* x    = (const float*)d_in[0];
  const float* W_in = (const float*)d_in[1];
  const float* b_in = (const float*)d_in[2];
  const float* eps  = (const float*)d_in[3];
  const float* W1   = (const float*)d_in[4];
  const float* b1   = (const float*)d_in[5];
  const float* gam  = (const float*)d_in[6];
  const float* bet  = (const float*)d_in[7];
  const float* W2   = (const float*)d_in[8];
  const float* b2   = (const float*)d_in[9];
  const float* Wo1  = (const float*)d_in[10];
  const float* bo1  = (const float*)d_in[11];
  const float* Wo2  = (const float*)d_in[12];
  const float* bo2  = (const float*)d_in[13];
  const int* ei     = (const int*)d_in[14];
  const int* batch  = (const int*)d_in[15];
  float* out = (float*)d_out;

  const int* e_src = ei;
  const int* e_dst = ei + NE;

  char* p = (char*)d_ws;
  float* h = (float*)p;        p += (size_t)NN * 64 * 4;
  float* agg = (float*)p;      p += (size_t)NN * 64 * 4;
  int* csr = (int*)p;          p += (size_t)NE * 4;
  int* cnt = (int*)p;          p += (size_t)NN * 4;
  int* offs = (int*)p;         p += (size_t)NN * 4;
  int* cursor = (int*)p;       p += (size_t)NN * 4;
  int* bsum = (int*)p;         p += 512 * 4;
  p = align_up(p, 256);
  float* pooled = (float*)p;   p += (size_t)NGRAPH * 64 * 4;

  const int SCAN_BLOCKS = (NN + 255) / 256;  // 391

  hipMemsetAsync(cnt, 0, (size_t)NN * 4, stream);
  hipMemsetAsync(pooled, 0, (size_t)NGRAPH * 64 * 4, stream);

  k_count<<<NE / 256, 256, 0, stream>>>(e_dst, cnt);
  k_scan1<<<SCAN_BLOCKS, 256, 0, stream>>>(cnt, offs, bsum, NN);
  k_scan2<<<1, 512, 0, stream>>>(bsum, SCAN_BLOCKS);
  k_scan3<<<SCAN_BLOCKS, 256, 0, stream>>>(offs, bsum, cursor, NN);
  k_fill<<<NE / 256, 256, 0, stream>>>(e_src, e_dst, cursor, csr);

  k_lin_in<<<NN / (4 * 4), 256, 0, stream>>>(x, W_in, b_in, h);

  for (int l = 0; l < NLAYERS; l++) {
    k_agg<<<NN * 16 / 256, 256, 0, stream>>>(h, csr, offs, cnt, agg);
    k_mlp<<<NN / 32, 256, 0, stream>>>(h, agg,
        W1 + (size_t)l * 64 * 128, b1 + (size_t)l * 128,
        gam + (size_t)l * 128, bet + (size_t)l * 128,
        W2 + (size_t)l * 128 * 64, b2 + (size_t)l * 64,
        eps + l);
  }

  k_pool<<<SCAN_BLOCKS, 256, 0, stream>>>(h, batch, pooled, NN);
  k_out<<<1, 256, 0, stream>>>(pooled, Wo1, bo1, Wo2, bo2, out);
}